// Round 1
// baseline (197.314 us; speedup 1.0000x reference)
//
#include <hip/hip_runtime.h>

#define NWIN 4096
#define DIM 96
#define HEADS 6
#define HD 16
#define NTOK 64

typedef __bf16 bf16x8 __attribute__((ext_vector_type(8)));
typedef __bf16 bf16x4 __attribute__((ext_vector_type(4)));
typedef float  f32x4  __attribute__((ext_vector_type(4)));

// d_ws layout
#define WS_QKVW 0                   // 288*96 bf16 = 55296 B
#define WS_PROJW 55296              // 96*96 bf16  = 18432 B
#define WS_BIAS 73728               // 6*64*64 f32 = 98304 B
#define WS_TOTAL 172032

__device__ __forceinline__ f32x4 mfma16(bf16x8 a, bf16x8 b, f32x4 c) {
  return __builtin_amdgcn_mfma_f32_16x16x32_bf16(a, b, c, 0, 0, 0);
}

// load 8 consecutive f32 and convert to bf16x8 (16B-aligned source)
__device__ __forceinline__ bf16x8 cvt8(const float* p) {
  const float4* q = (const float4*)p;
  float4 a = q[0];
  float4 b = q[1];
  bf16x8 r;
  r[0] = (__bf16)a.x; r[1] = (__bf16)a.y; r[2] = (__bf16)a.z; r[3] = (__bf16)a.w;
  r[4] = (__bf16)b.x; r[5] = (__bf16)b.y; r[6] = (__bf16)b.z; r[7] = (__bf16)b.w;
  return r;
}

// Pre-pass: weights -> bf16, gather relative-position bias -> f32 [6][64][64].
__global__ void prep_kernel(const float* __restrict__ qkv_w,
                            const float* __restrict__ proj_w,
                            const float* __restrict__ rpb,
                            const int* __restrict__ rpi,
                            char* __restrict__ ws) {
  int i = blockIdx.x * blockDim.x + threadIdx.x;
  __bf16* qw = (__bf16*)(ws + WS_QKVW);
  __bf16* pw = (__bf16*)(ws + WS_PROJW);
  float* bias = (float*)(ws + WS_BIAS);
  if (i < 288 * 96) qw[i] = (__bf16)qkv_w[i];
  int j = i - 288 * 96;
  if (j >= 0 && j < 96 * 96) pw[j] = (__bf16)proj_w[j];
  int t = i - (288 * 96 + 96 * 96);
  if (t >= 0 && t < HEADS * 64 * 64) {
    int h = t >> 12;        // head
    int im = t & 4095;      // i*64+m
    bias[t] = rpb[rpi[im] * HEADS + h];
  }
}

// One block = one window. 6 waves, wave w owns head w end-to-end until proj.
template <bool USE_WS>
__global__ __launch_bounds__(384, 3) void win_attn(
    const float* __restrict__ x,
    const int* __restrict__ rpi,
    const float* __restrict__ qkv_w,
    const float* __restrict__ qkv_b,
    const float* __restrict__ proj_w,
    const float* __restrict__ proj_b,
    const float* __restrict__ rpb,
    const char* __restrict__ ws,
    float* __restrict__ out) {
  // per-head region (4224 bf16 = 8448 B): q[64][24] | k[64][24] | vT[16][72]
  // P chunk [64][40] overlays q/k (dead by then). ao[64][104] shared across waves.
  // total: 6*8448 + 13312 = 64000 B  -> 2 blocks/CU
  __shared__ __align__(16) __bf16 lds[HEADS * 4224 + 64 * 104];

  const int tid = (int)threadIdx.x;
  const int wv = tid >> 6;     // wave = head, 0..5
  const int lane = tid & 63;
  const int l16 = lane & 15;
  const int lq = lane >> 4;    // 0..3
  const int b = (int)blockIdx.x;

  __bf16* region = lds + wv * 4224;
  __bf16* qh = region;             // [64][24]
  __bf16* kh = region + 1536;      // [64][24]
  __bf16* vh = region + 3072;      // vT [16][72]
  __bf16* Pc = region;             // [64][40] overlay of q/k
  __bf16* ao = lds + HEADS * 4224; // [64][104]

  const float* xw = x + (size_t)b * (NTOK * DIM);
  const __bf16* qwb = (const __bf16*)(ws + WS_QKVW);
  const __bf16* pwb = (const __bf16*)(ws + WS_PROJW);
  const float* biasw = (const float*)(ws + WS_BIAS) + wv * 4096;

  bf16x8 zf;
#pragma unroll
  for (int e = 0; e < 8; ++e) zf[e] = (__bf16)0.0f;

  // ---- x A-fragments (A[i][k]: row=l16+16mt, k=8*lq+e+32ks) ----
  bf16x8 xa[4][3];
#pragma unroll
  for (int mt = 0; mt < 4; ++mt)
#pragma unroll
    for (int ks = 0; ks < 3; ++ks)
      xa[mt][ks] = cvt8(xw + (16 * mt + l16) * DIM + 32 * ks + 8 * lq);

  // ---- qkv GEMM: wave w computes column tiles {q_w, k_w, v_w} ----
#pragma unroll
  for (int s = 0; s < 3; ++s) {
    const int ocol = (s * HEADS + wv) * 16 + l16;  // qkv_w row (output feature)
    bf16x8 wb[3];
#pragma unroll
    for (int ks = 0; ks < 3; ++ks) {
      if constexpr (USE_WS)
        wb[ks] = *(const bf16x8*)(qwb + ocol * 96 + 32 * ks + 8 * lq);
      else
        wb[ks] = cvt8(qkv_w + ocol * 96 + 32 * ks + 8 * lq);
    }
    const float qb = qkv_b[ocol];
#pragma unroll
    for (int mt = 0; mt < 4; ++mt) {
      f32x4 acc = {0.f, 0.f, 0.f, 0.f};
#pragma unroll
      for (int ks = 0; ks < 3; ++ks) acc = mfma16(xa[mt][ks], wb[ks], acc);
      // D-frag: row = 16mt + 4lq + r, col = l16
      if (s == 0) {
#pragma unroll
        for (int r = 0; r < 4; ++r)
          qh[(16 * mt + 4 * lq + r) * 24 + l16] = (__bf16)((acc[r] + qb) * 0.25f);
      } else if (s == 1) {
#pragma unroll
        for (int r = 0; r < 4; ++r)
          kh[(16 * mt + 4 * lq + r) * 24 + l16] = (__bf16)(acc[r] + qb);
      } else {
        bf16x4 t;
#pragma unroll
        for (int r = 0; r < 4; ++r) t[r] = (__bf16)(acc[r] + qb);
        // vT[d=l16][m=16mt+4lq+r], r contiguous -> 8B store
        *(bf16x4*)(vh + l16 * 72 + 16 * mt + 4 * lq) = t;
      }
    }
  }
  asm volatile("s_waitcnt lgkmcnt(0)" ::: "memory");

  // ---- QK^T (K padded 16->32; lanes with lq>=2 supply zeros) ----
  bf16x8 qa[4], kb[4];
#pragma unroll
  for (int t4 = 0; t4 < 4; ++t4) {
    if (lq < 2) {
      qa[t4] = *(const bf16x8*)(qh + (16 * t4 + l16) * 24 + 8 * lq);
      kb[t4] = *(const bf16x8*)(kh + (16 * t4 + l16) * 24 + 8 * lq);
    } else {
      qa[t4] = zf;
      kb[t4] = zf;
    }
  }

  f32x4 sacc[4][4];
#pragma unroll
  for (int mt = 0; mt < 4; ++mt)
#pragma unroll
    for (int nt = 0; nt < 4; ++nt) {
      f32x4 acc = {0.f, 0.f, 0.f, 0.f};
      sacc[mt][nt] = mfma16(qa[mt], kb[nt], acc);
    }

  // ---- + relative position bias ----
#pragma unroll
  for (int mt = 0; mt < 4; ++mt)
#pragma unroll
    for (int r = 0; r < 4; ++r) {
      const int row = 16 * mt + 4 * lq + r;
#pragma unroll
      for (int nt = 0; nt < 4; ++nt) {
        const int col = 16 * nt + l16;
        float bv;
        if constexpr (USE_WS)
          bv = biasw[row * 64 + col];
        else
          bv = rpb[rpi[row * 64 + col] * HEADS + wv];
        sacc[mt][nt][r] += bv;
      }
    }

  // ---- softmax over rows (row owners = 16-lane groups; shfl_xor 1/2/4/8) ----
  float sm[4][4];
#pragma unroll
  for (int mt = 0; mt < 4; ++mt)
#pragma unroll
    for (int r = 0; r < 4; ++r) {
      float m = sacc[mt][0][r];
#pragma unroll
      for (int nt = 1; nt < 4; ++nt) m = fmaxf(m, sacc[mt][nt][r]);
#pragma unroll
      for (int d = 1; d < 16; d <<= 1) m = fmaxf(m, __shfl_xor(m, d, 64));
      float t = 0.f;
#pragma unroll
      for (int nt = 0; nt < 4; ++nt) {
        float e = __expf(sacc[mt][nt][r] - m);
        sacc[mt][nt][r] = e;
        t += e;
      }
#pragma unroll
      for (int d = 1; d < 16; d <<= 1) t += __shfl_xor(t, d, 64);
      sm[mt][r] = t;  // unnormalized row sum
    }

  // ---- PV: P streamed through LDS in two 64x32 chunks (K-steps) ----
  f32x4 oacc[4];
#pragma unroll
  for (int mt = 0; mt < 4; ++mt) {
    f32x4 z4 = {0.f, 0.f, 0.f, 0.f};
    oacc[mt] = z4;
  }
#pragma unroll
  for (int c = 0; c < 2; ++c) {
#pragma unroll
    for (int j = 0; j < 2; ++j) {
      const int nt = 2 * c + j;
#pragma unroll
      for (int mt = 0; mt < 4; ++mt)
#pragma unroll
        for (int r = 0; r < 4; ++r)
          Pc[(16 * mt + 4 * lq + r) * 40 + 16 * j + l16] = (__bf16)sacc[mt][nt][r];
    }
    asm volatile("s_waitcnt lgkmcnt(0)" ::: "memory");
    // B-frag: B[m][d] = vT[d=l16][m=32c+8lq+e]
    const bf16x8 vb = *(const bf16x8*)(vh + l16 * 72 + 32 * c + 8 * lq);
#pragma unroll
    for (int mt = 0; mt < 4; ++mt) {
      bf16x8 pa = *(const bf16x8*)(Pc + (16 * mt + l16) * 40 + 8 * lq);
      oacc[mt] = mfma16(pa, vb, oacc[mt]);
    }
    asm volatile("s_waitcnt lgkmcnt(0)" ::: "memory");
  }

  // ---- normalize + stage attn-out ----
#pragma unroll
  for (int mt = 0; mt < 4; ++mt)
#pragma unroll
    for (int r = 0; r < 4; ++r) {
      const float rv = 1.0f / sm[mt][r];
      ao[(16 * mt + 4 * lq + r) * 104 + 16 * wv + l16] = (__bf16)(oacc[mt][r] * rv);
    }

  __syncthreads();

  // ---- proj: out tile column wv ----
  bf16x8 wpb[3];
#pragma unroll
  for (int ks = 0; ks < 3; ++ks) {
    if constexpr (USE_WS)
      wpb[ks] = *(const bf16x8*)(pwb + (16 * wv + l16) * 96 + 32 * ks + 8 * lq);
    else
      wpb[ks] = cvt8(proj_w + (16 * wv + l16) * 96 + 32 * ks + 8 * lq);
  }
  const float pb2 = proj_b[16 * wv + l16];
  float* outw = out + (size_t)b * (NTOK * DIM);
#pragma unroll
  for (int mt = 0; mt < 4; ++mt) {
    f32x4 acc = {0.f, 0.f, 0.f, 0.f};
#pragma unroll
    for (int ks = 0; ks < 3; ++ks) {
      bf16x8 aa = *(const bf16x8*)(ao + (16 * mt + l16) * 104 + 32 * ks + 8 * lq);
      acc = mfma16(aa, wpb[ks], acc);
    }
#pragma unroll
    for (int r = 0; r < 4; ++r)
      outw[(16 * mt + 4 * lq + r) * 96 + 16 * wv + l16] = acc[r] + pb2;
  }
}

extern "C" void kernel_launch(void* const* d_in, const int* in_sizes, int n_in,
                              void* d_out, int out_size, void* d_ws, size_t ws_size,
                              hipStream_t stream) {
  const float* x      = (const float*)d_in[0];
  const int*   rpi    = (const int*)d_in[1];
  const float* qkv_w  = (const float*)d_in[2];
  const float* qkv_b  = (const float*)d_in[3];
  const float* proj_w = (const float*)d_in[4];
  const float* proj_b = (const float*)d_in[5];
  const float* rpb    = (const float*)d_in[6];
  float* out = (float*)d_out;

  if (ws_size >= (size_t)WS_TOTAL) {
    prep_kernel<<<240, 256, 0, stream>>>(qkv_w, proj_w, rpb, rpi, (char*)d_ws);
    win_attn<true><<<NWIN, 384, 0, stream>>>(x, rpi, qkv_w, qkv_b, proj_w,
                                             proj_b, rpb, (const char*)d_ws, out);
  } else {
    win_attn<false><<<NWIN, 384, 0, stream>>>(x, rpi, qkv_w, qkv_b, proj_w,
                                              proj_b, rpb, (const char*)d_ws, out);
  }
}

// Round 2
// 133.010 us; speedup vs baseline: 1.4835x; 1.4835x over previous
//
#include <hip/hip_runtime.h>

#define NWIN 4096
#define DIM 96
#define HEADS 6
#define NTOK 64

typedef __bf16 bf16x8 __attribute__((ext_vector_type(8)));
typedef __bf16 bf16x4 __attribute__((ext_vector_type(4)));
typedef float  f32x4  __attribute__((ext_vector_type(4)));

// d_ws layout
#define WS_QKVW 0                   // 288*96 bf16 = 55296 B
#define WS_PROJW 55296              // 96*96 bf16  = 18432 B
#define WS_BIAS 73728               // 6*16*64 float4 = 98304 B (frag-ordered)
#define WS_TOTAL 172032

__device__ __forceinline__ f32x4 mfma16(bf16x8 a, bf16x8 b, f32x4 c) {
  return __builtin_amdgcn_mfma_f32_16x16x32_bf16(a, b, c, 0, 0, 0);
}

__device__ __forceinline__ bf16x8 cvt8(const float* p) {
  const float4* q = (const float4*)p;
  float4 a = q[0];
  float4 b = q[1];
  bf16x8 r;
  r[0] = (__bf16)a.x; r[1] = (__bf16)a.y; r[2] = (__bf16)a.z; r[3] = (__bf16)a.w;
  r[4] = (__bf16)b.x; r[5] = (__bf16)b.y; r[6] = (__bf16)b.z; r[7] = (__bf16)b.w;
  return r;
}

// Pre-pass: weights -> bf16; bias gathered into MFMA-fragment order:
// bias[((h*16 + bq*4 + a)*64 + lane)*4 + r] = rpb[rpi[qrow*64+kcol]*6+h]
// with qrow = 16*bq + (lane&15), kcol = 16*a + 4*(lane>>4) + r.
__global__ void prep_kernel(const float* __restrict__ qkv_w,
                            const float* __restrict__ proj_w,
                            const float* __restrict__ rpb,
                            const int* __restrict__ rpi,
                            char* __restrict__ ws) {
  int i = blockIdx.x * blockDim.x + threadIdx.x;
  __bf16* qw = (__bf16*)(ws + WS_QKVW);
  __bf16* pw = (__bf16*)(ws + WS_PROJW);
  float* bias = (float*)(ws + WS_BIAS);
  if (i < 288 * 96) qw[i] = (__bf16)qkv_w[i];
  int j = i - 288 * 96;
  if (j >= 0 && j < 96 * 96) pw[j] = (__bf16)proj_w[j];
  int t = i - (288 * 96 + 96 * 96);
  if (t >= 0 && t < HEADS * 16 * 64 * 4) {
    int r = t & 3;
    int lane = (t >> 2) & 63;
    int ba = (t >> 8) & 15;
    int h = t >> 12;
    int bq = ba >> 2, a = ba & 3;
    int l16 = lane & 15, lq = lane >> 4;
    int qrow = 16 * bq + l16;
    int kcol = 16 * a + 4 * lq + r;
    bias[t] = rpb[rpi[qrow * 64 + kcol] * HEADS + h];
  }
}

// One block = one window; 6 waves, wave w owns head w until proj.
template <bool USE_WS>
__global__ __launch_bounds__(384, 5) void win_attn(
    const float* __restrict__ x,
    const int* __restrict__ rpi,
    const float* __restrict__ qkv_w,
    const float* __restrict__ qkv_b,
    const float* __restrict__ proj_w,
    const float* __restrict__ proj_b,
    const float* __restrict__ rpb,
    const char* __restrict__ ws,
    float* __restrict__ out) {
  // per-head region (4224 bf16): q[64][24] | k[64][24] | vT[16][72]
  // Pt[16][72] overlays k (dead after kb hoist). ao[64][104] overlays all
  // regions (post-barrier). total 50688 B -> 3 blocks/CU.
  __shared__ __align__(16) __bf16 lds[HEADS * 4224];

  const int tid = (int)threadIdx.x;
  const int wv = tid >> 6;
  const int lane = tid & 63;
  const int l16 = lane & 15;
  const int lq = lane >> 4;
  const int b = (int)blockIdx.x;

  __bf16* region = lds + wv * 4224;
  __bf16* qh = region;             // [64][24]
  __bf16* kh = region + 1536;      // [64][24]
  __bf16* vh = region + 3072;      // vT [16][72]
  __bf16* Pt = region + 1536;      // [16][72] overlay of kh
  __bf16* ao = lds;                // [64][104] overlay (post-barrier)

  const float* xw = x + (size_t)b * (NTOK * DIM);
  const __bf16* qwb = (const __bf16*)(ws + WS_QKVW);
  const __bf16* pwb = (const __bf16*)(ws + WS_PROJW);
  const float4* bias4 = (const float4*)(ws + WS_BIAS) + (wv << 10);

  bf16x8 zf = {};

  // ---- x A-fragments ----
  bf16x8 xa[4][3];
#pragma unroll
  for (int mt = 0; mt < 4; ++mt)
#pragma unroll
    for (int ks = 0; ks < 3; ++ks)
      xa[mt][ks] = cvt8(xw + (16 * mt + l16) * DIM + 32 * ks + 8 * lq);

  // ---- qkv GEMM: wave w computes {q_w, k_w, v_w} ----
#pragma unroll
  for (int s = 0; s < 3; ++s) {
    const int ocol = (s * HEADS + wv) * 16 + l16;
    bf16x8 wb[3];
#pragma unroll
    for (int ks = 0; ks < 3; ++ks) {
      if constexpr (USE_WS)
        wb[ks] = *(const bf16x8*)(qwb + ocol * 96 + 32 * ks + 8 * lq);
      else
        wb[ks] = cvt8(qkv_w + ocol * 96 + 32 * ks + 8 * lq);
    }
    const float qb = qkv_b[ocol];
#pragma unroll
    for (int mt = 0; mt < 4; ++mt) {
      f32x4 acc = {0.f, 0.f, 0.f, 0.f};
#pragma unroll
      for (int ks = 0; ks < 3; ++ks) acc = mfma16(xa[mt][ks], wb[ks], acc);
      if (s == 0) {
#pragma unroll
        for (int r = 0; r < 4; ++r)
          qh[(16 * mt + 4 * lq + r) * 24 + l16] = (__bf16)((acc[r] + qb) * 0.25f);
      } else if (s == 1) {
#pragma unroll
        for (int r = 0; r < 4; ++r)
          kh[(16 * mt + 4 * lq + r) * 24 + l16] = (__bf16)(acc[r] + qb);
      } else {
        bf16x4 t;
#pragma unroll
        for (int r = 0; r < 4; ++r) t[r] = (__bf16)(acc[r] + qb);
        *(bf16x4*)(vh + l16 * 72 + 16 * mt + 4 * lq) = t;
      }
    }
  }
  asm volatile("s_waitcnt lgkmcnt(0)" ::: "memory");

  // ---- hoist K A-frags and V B-frags (k LDS dead afterwards) ----
  bf16x8 kb[4];
#pragma unroll
  for (int a = 0; a < 4; ++a)
    kb[a] = (lq < 2) ? *(const bf16x8*)(kh + (16 * a + l16) * 24 + 8 * lq) : zf;
  bf16x8 vbf[2];
#pragma unroll
  for (int c = 0; c < 2; ++c)
    vbf[c] = *(const bf16x8*)(vh + l16 * 72 + 32 * c + 8 * lq);
  asm volatile("s_waitcnt lgkmcnt(0)" ::: "memory");  // reads done before Pt overwrite

  f32x4 oacc[4];
#pragma unroll
  for (int mt = 0; mt < 4; ++mt) {
    f32x4 z4 = {0.f, 0.f, 0.f, 0.f};
    oacc[mt] = z4;
  }

  // ---- attention, one q-tile (16 rows) at a time; S^T = K*Q^T, bias = C-init ----
  f32x4 bc[4], bn[4];
  if constexpr (USE_WS) {
#pragma unroll
    for (int a = 0; a < 4; ++a) {
      float4 t = bias4[a * 64 + lane];
      bc[a][0] = t.x; bc[a][1] = t.y; bc[a][2] = t.z; bc[a][3] = t.w;
    }
  }

#pragma unroll
  for (int bq = 0; bq < 4; ++bq) {
    if constexpr (USE_WS) {
      if (bq < 3) {
#pragma unroll
        for (int a = 0; a < 4; ++a) {
          float4 t = bias4[((bq + 1) * 4 + a) * 64 + lane];
          bn[a][0] = t.x; bn[a][1] = t.y; bn[a][2] = t.z; bn[a][3] = t.w;
        }
      }
    } else {
#pragma unroll
      for (int a = 0; a < 4; ++a)
#pragma unroll
        for (int r = 0; r < 4; ++r)
          bc[a][r] = rpb[rpi[(16 * bq + l16) * 64 + 16 * a + 4 * lq + r] * HEADS + wv];
    }

    const bf16x8 qbf =
        (lq < 2) ? *(const bf16x8*)(qh + (16 * bq + l16) * 24 + 8 * lq) : zf;

    f32x4 s[4];
#pragma unroll
    for (int a = 0; a < 4; ++a) s[a] = mfma16(kb[a], qbf, bc[a]);

    // full row (16 vals) per lane; reduce in-reg + across lq groups
    float m = s[0][0];
#pragma unroll
    for (int a = 0; a < 4; ++a)
#pragma unroll
      for (int r = 0; r < 4; ++r) m = fmaxf(m, s[a][r]);
    m = fmaxf(m, __shfl_xor(m, 16));
    m = fmaxf(m, __shfl_xor(m, 32));
    float t = 0.f;
#pragma unroll
    for (int a = 0; a < 4; ++a)
#pragma unroll
      for (int r = 0; r < 4; ++r) {
        float e = __expf(s[a][r] - m);
        s[a][r] = e;
        t += e;
      }
    t += __shfl_xor(t, 16);
    t += __shfl_xor(t, 32);
    const float rv = 1.0f / t;

    // normalized P tile -> LDS [16][72]
#pragma unroll
    for (int a = 0; a < 4; ++a) {
      bf16x4 p;
#pragma unroll
      for (int r = 0; r < 4; ++r) p[r] = (__bf16)(s[a][r] * rv);
      *(bf16x4*)(Pt + l16 * 72 + 16 * a + 4 * lq) = p;
    }
    asm volatile("s_waitcnt lgkmcnt(0)" ::: "memory");

    // PV for this q-tile
#pragma unroll
    for (int c = 0; c < 2; ++c) {
      const bf16x8 pa = *(const bf16x8*)(Pt + l16 * 72 + 32 * c + 8 * lq);
      oacc[bq] = mfma16(pa, vbf[c], oacc[bq]);
    }
    asm volatile("s_waitcnt lgkmcnt(0)" ::: "memory");  // drain before next overwrite

    if constexpr (USE_WS) {
#pragma unroll
      for (int a = 0; a < 4; ++a) bc[a] = bn[a];
    }
  }

  // ---- stage attn-out (ao overlays head regions; must barrier first) ----
  __syncthreads();
#pragma unroll
  for (int mt = 0; mt < 4; ++mt)
#pragma unroll
    for (int r = 0; r < 4; ++r)
      ao[(16 * mt + 4 * lq + r) * 104 + 16 * wv + l16] = (__bf16)oacc[mt][r];
  __syncthreads();

  // ---- proj ----
  bf16x8 wpb[3];
#pragma unroll
  for (int ks = 0; ks < 3; ++ks) {
    if constexpr (USE_WS)
      wpb[ks] = *(const bf16x8*)(pwb + (16 * wv + l16) * 96 + 32 * ks + 8 * lq);
    else
      wpb[ks] = cvt8(proj_w + (16 * wv + l16) * 96 + 32 * ks + 8 * lq);
  }
  const float pb2 = proj_b[16 * wv + l16];
  float* outw = out + (size_t)b * (NTOK * DIM);
#pragma unroll
  for (int mt = 0; mt < 4; ++mt) {
    f32x4 acc = {0.f, 0.f, 0.f, 0.f};
#pragma unroll
    for (int ks = 0; ks < 3; ++ks) {
      bf16x8 aa = *(const bf16x8*)(ao + (16 * mt + l16) * 104 + 32 * ks + 8 * lq);
      acc = mfma16(aa, wpb[ks], acc);
    }
#pragma unroll
    for (int r = 0; r < 4; ++r)
      outw[(16 * mt + 4 * lq + r) * 96 + 16 * wv + l16] = acc[r] + pb2;
  }
}

extern "C" void kernel_launch(void* const* d_in, const int* in_sizes, int n_in,
                              void* d_out, int out_size, void* d_ws, size_t ws_size,
                              hipStream_t stream) {
  const float* x      = (const float*)d_in[0];
  const int*   rpi    = (const int*)d_in[1];
  const float* qkv_w  = (const float*)d_in[2];
  const float* qkv_b  = (const float*)d_in[3];
  const float* proj_w = (const float*)d_in[4];
  const float* proj_b = (const float*)d_in[5];
  const float* rpb    = (const float*)d_in[6];
  float* out = (float*)d_out;

  if (ws_size >= (size_t)WS_TOTAL) {
    prep_kernel<<<240, 256, 0, stream>>>(qkv_w, proj_w, rpb, rpi, (char*)d_ws);
    win_attn<true><<<NWIN, 384, 0, stream>>>(x, rpi, qkv_w, qkv_b, proj_w,
                                             proj_b, rpb, (const char*)d_ws, out);
  } else {
    win_attn<false><<<NWIN, 384, 0, stream>>>(x, rpi, qkv_w, qkv_b, proj_w,
                                              proj_b, rpb, (const char*)d_ws, out);
  }
}